// Round 7
// baseline (369.769 us; speedup 1.0000x reference)
//
#include <hip/hip_runtime.h>

#ifndef __has_builtin
#define __has_builtin(x) 0
#endif

__device__ __forceinline__ float fast_exp2(float x) {
#if __has_builtin(__builtin_amdgcn_exp2f)
    return __builtin_amdgcn_exp2f(x);
#else
    return exp2f(x);
#endif
}

// Canonical CDNA wave64 sum via DPP (VALU pipe, not DS):
// row_shr 1/2/4/8 (bound_ctrl: invalid->0), then row_bcast15 (rows 1,3),
// row_bcast31 (rows 2,3). Lane 63 ends with the full 64-lane sum.
__device__ __forceinline__ float wave_sum_dpp(float x) {
    int v;
    v = __builtin_amdgcn_update_dpp(0, __float_as_int(x), 0x111, 0xf, 0xf, true);
    x += __int_as_float(v);
    v = __builtin_amdgcn_update_dpp(0, __float_as_int(x), 0x112, 0xf, 0xf, true);
    x += __int_as_float(v);
    v = __builtin_amdgcn_update_dpp(0, __float_as_int(x), 0x114, 0xf, 0xf, true);
    x += __int_as_float(v);
    v = __builtin_amdgcn_update_dpp(0, __float_as_int(x), 0x118, 0xf, 0xf, true);
    x += __int_as_float(v);
    v = __builtin_amdgcn_update_dpp(0, __float_as_int(x), 0x142, 0xa, 0xf, false);
    x += __int_as_float(v);
    v = __builtin_amdgcn_update_dpp(0, __float_as_int(x), 0x143, 0xc, 0xf, false);
    x += __int_as_float(v);
    return x;
}

// Block-wide barrier WITHOUT the vmcnt(0) drain that __syncthreads emits.
// Only LDS ops (sP/sInvD) need cross-wave visibility; in-flight global
// prefetch loads (into SSA scalars, not memory) legally stay outstanding.
__device__ __forceinline__ void sync_lds() {
    asm volatile("s_waitcnt lgkmcnt(0)" ::: "memory");
    __builtin_amdgcn_s_barrier();
    asm volatile("" ::: "memory");
}

constexpr int   kB      = 256;
constexpr int   kC      = 1024;
constexpr int   kG      = 13;
constexpr int   kP      = kG * kG;                // 169
constexpr int   kRP     = 13;                     // positions per part = one row
constexpr float kEps    = 1e-6f;
constexpr float kZ      = 17.079468445347132f;    // 2*pi*e
constexpr float kLog2e  = 1.4426950408889634f;
constexpr float kInv169 = 1.0f / 169.0f;
constexpr float kScale  = 1.0f / (256.0f * 1024.0f);

// 13 named scalars instead of float[13]: R3-R6 measured ~242 MB/dispatch of
// scratch traffic (WRITE_SIZE 236,552 KB = 924 B/thread) that no
// launch-bounds/waves_per_eu knob moved -> the arrays were never
// SROA-promoted; every access was scratch, flushed at each "memory" asm.
// Named members have no alloca to demote (guide rule #20).
struct Row {
    float f0, f1, f2, f3, f4, f5, f6, f7, f8, f9, f10, f11, f12;
};

#define R13(F) F(0) F(1) F(2) F(3) F(4) F(5) F(6) F(7) F(8) F(9) F(10) F(11) F(12)

// One pipelined row step. PART (= grid row h) compile-time; LAST skips the
// prefetch. cur holds raw x for row PART; nxt receives row PART+1's
// prefetch. Position order and fmaf sequence identical to the verified
// R2..R6 kernels -> absmax stays 0.
template<int PART, bool LAST>
__device__ __forceinline__ void do_row(
    const float* __restrict__ xb, int tid, int lane, int wid,
    Row& cur, Row& nxt,
    float& S0, float& S1x, float& S1y, float& S2x, float& S2y,
    float* __restrict__ sP, float* __restrict__ sInvD)
{
    constexpr int START = PART * kRP;

    // 1) prefetch next row: 13 loads issued now, consumed next do_row.
    //    They stay in flight across the lgkm-only barriers below.
    if (!LAST) {
        const float* __restrict__ xn = xb + (size_t)(START + kRP) * kC + tid;
        #define LOADN(i) nxt.f##i = xn[(size_t)(i) * kC];
        R13(LOADN)
        #undef LOADN
    }

    // 2) exp (first use of cur's loads -> compiler-inserted vmcnt wait here)
    #define EXPC(i) cur.f##i = fast_exp2(cur.f##i * kLog2e);
    R13(EXPC)
    #undef EXPC

    // 3) per-position wave partial sums on the VALU pipe
    #define DPPC(i) { const float s_ = wave_sum_dpp(cur.f##i); \
                      if (lane == 63) sP[(i) * 16 + wid] = s_; }
    R13(DPPC)
    #undef DPPC
    sync_lds();

    // 4) 16-way cross-wave tree -> per-position inverse denominator
    if (tid < kRP) {
        float d = 0.f;
        #pragma unroll
        for (int w = 0; w < 16; ++w)
            d += sP[tid * 16 + w];
        sInvD[tid] = 1.0f / (d + 1e-30f);
    }
    sync_lds();

    // 5) stats: h = PART constant, w = i (fx=(float)(h+1), fy=(float)(w+1))
    const float fx = (float)(PART + 1);
    #define FMAC(i) { const float f_  = cur.f##i * sInvD[(i)];           \
                      const float fy_ = (float)((i) + 1);                \
                      S0  += f_;                                         \
                      S1x  = fmaf(fx,        f_, S1x);                   \
                      S1y  = fmaf(fy_,       f_, S1y);                   \
                      S2x  = fmaf(fx * fx,   f_, S2x);                   \
                      S2y  = fmaf(fy_ * fy_, f_, S2y); }
    R13(FMAC)
    #undef FMAC
    // sP/sInvD reuse across rows is race-free: writes for row k+1 happen
    // only after every wave passed barrier2 of row k.
}

// ---------------------------------------------------------------------------
// Fully fused, software-pipelined kernel: one block per batch b, 1024
// threads (thread = channel). 13 rows of 13 positions, double-buffered
// scalar Rows, raw lgkm-only barriers so prefetch loads stay in flight.
// Grid = 256 blocks = 1 block/CU; waves_per_eu(4,4) pins the 128-VGPR
// budget (16 waves x 128 = full pool) now that values live in registers.
// Input bytes touched exactly once (177 MB -> HBM floor ~28 us).
// ---------------------------------------------------------------------------
__global__ __launch_bounds__(1024)
__attribute__((amdgpu_waves_per_eu(4, 4)))
void fused_kernel(const float* __restrict__ x, float* __restrict__ out)
{
    __shared__ float sP[kRP * 16];        // per-(position, wave) partials
    __shared__ float sInvD[kRP];
    __shared__ float sred[16];

    const int tid  = threadIdx.x;
    const int lane = tid & 63;
    const int wid  = tid >> 6;
    const int b    = blockIdx.x;

    const float* __restrict__ xb = x + (size_t)b * kP * kC;

    Row e0, e1;
    float S0 = 0.f, S1x = 0.f, S1y = 0.f, S2x = 0.f, S2y = 0.f;

    // prologue: load row 0
    {
        const float* __restrict__ xc = xb + tid;
        #define LOAD0(i) e0.f##i = xc[(size_t)(i) * kC];
        R13(LOAD0)
        #undef LOAD0
    }

    do_row< 0, false>(xb, tid, lane, wid, e0, e1, S0, S1x, S1y, S2x, S2y, sP, sInvD);
    do_row< 1, false>(xb, tid, lane, wid, e1, e0, S0, S1x, S1y, S2x, S2y, sP, sInvD);
    do_row< 2, false>(xb, tid, lane, wid, e0, e1, S0, S1x, S1y, S2x, S2y, sP, sInvD);
    do_row< 3, false>(xb, tid, lane, wid, e1, e0, S0, S1x, S1y, S2x, S2y, sP, sInvD);
    do_row< 4, false>(xb, tid, lane, wid, e0, e1, S0, S1x, S1y, S2x, S2y, sP, sInvD);
    do_row< 5, false>(xb, tid, lane, wid, e1, e0, S0, S1x, S1y, S2x, S2y, sP, sInvD);
    do_row< 6, false>(xb, tid, lane, wid, e0, e1, S0, S1x, S1y, S2x, S2y, sP, sInvD);
    do_row< 7, false>(xb, tid, lane, wid, e1, e0, S0, S1x, S1y, S2x, S2y, sP, sInvD);
    do_row< 8, false>(xb, tid, lane, wid, e0, e1, S0, S1x, S1y, S2x, S2y, sP, sInvD);
    do_row< 9, false>(xb, tid, lane, wid, e1, e0, S0, S1x, S1y, S2x, S2y, sP, sInvD);
    do_row<10, false>(xb, tid, lane, wid, e0, e1, S0, S1x, S1y, S2x, S2y, sP, sInvD);
    do_row<11, false>(xb, tid, lane, wid, e1, e0, S0, S1x, S1y, S2x, S2y, sP, sInvD);
    do_row<12, true >(xb, tid, lane, wid, e0, e1, S0, S1x, S1y, S2x, S2y, sP, sInvD);

    // det epilogue per (b, c) and block-wide mean contribution
    const float s   = S0 + kEps;
    const float is  = 1.0f / s;
    const float mx  = S1x * is;
    const float my  = S1y * is;
    const float nx  = S2x - mx * (2.0f * S1x - mx * S0);
    const float ny  = S2y - my * (2.0f * S1y - my * S0);
    const float t   = (nx + ny) * is * kInv169;
    float det = t * t * kZ;

    #pragma unroll
    for (int m = 1; m < 64; m <<= 1)
        det += __shfl_xor(det, m);

    if (lane == 0) sred[wid] = det;
    __syncthreads();
    if (wid == 0) {
        float v = (lane < 16) ? sred[lane] : 0.0f;
        #pragma unroll
        for (int m = 1; m < 16; m <<= 1)
            v += __shfl_xor(v, m);
        if (lane == 0) atomicAdd(out, v * kScale);
    }
}

extern "C" void kernel_launch(void* const* d_in, const int* in_sizes, int n_in,
                              void* d_out, int out_size, void* d_ws, size_t ws_size,
                              hipStream_t stream)
{
    const float* x   = (const float*)d_in[0];
    float*       out = (float*)d_out;

    // out is tiny (scalar compare); R1->R2 delta proved this memset is ~free.
    hipMemsetAsync(out, 0, sizeof(float) * (size_t)out_size, stream);
    fused_kernel<<<dim3(kB), dim3(1024), 0, stream>>>(x, out);
}

// Round 8
// 248.646 us; speedup vs baseline: 1.4871x; 1.4871x over previous
//
#include <hip/hip_runtime.h>

#ifndef __has_builtin
#define __has_builtin(x) 0
#endif

__device__ __forceinline__ float fast_exp2(float x) {
#if __has_builtin(__builtin_amdgcn_exp2f)
    return __builtin_amdgcn_exp2f(x);
#else
    return exp2f(x);
#endif
}

// Canonical CDNA wave64 sum via DPP (VALU pipe, not DS):
// row_shr 1/2/4/8 (bound_ctrl: invalid->0), then row_bcast15 (rows 1,3),
// row_bcast31 (rows 2,3). Lane 63 ends with the full 64-lane sum.
__device__ __forceinline__ float wave_sum_dpp(float x) {
    int v;
    v = __builtin_amdgcn_update_dpp(0, __float_as_int(x), 0x111, 0xf, 0xf, true);
    x += __int_as_float(v);
    v = __builtin_amdgcn_update_dpp(0, __float_as_int(x), 0x112, 0xf, 0xf, true);
    x += __int_as_float(v);
    v = __builtin_amdgcn_update_dpp(0, __float_as_int(x), 0x114, 0xf, 0xf, true);
    x += __int_as_float(v);
    v = __builtin_amdgcn_update_dpp(0, __float_as_int(x), 0x118, 0xf, 0xf, true);
    x += __int_as_float(v);
    v = __builtin_amdgcn_update_dpp(0, __float_as_int(x), 0x142, 0xa, 0xf, false);
    x += __int_as_float(v);
    v = __builtin_amdgcn_update_dpp(0, __float_as_int(x), 0x143, 0xc, 0xf, false);
    x += __int_as_float(v);
    return x;
}

constexpr int   kB      = 256;
constexpr int   kC      = 1024;
constexpr int   kG      = 13;
constexpr int   kP      = kG * kG;                // 169
constexpr int   kParts  = 4;
constexpr int   kMaxPP  = 43;                     // parts cover 42,42,42,43
constexpr float kEps    = 1e-6f;
constexpr float kZ      = 17.079468445347132f;    // 2*pi*e
constexpr float kLog2e  = 1.4426950408889634f;
constexpr float kInv169 = 1.0f / 169.0f;
constexpr float kScale  = 1.0f / (256.0f * 1024.0f);

// ---------------------------------------------------------------------------
// Fully fused kernel: one block per batch b, 1024 threads (thread = channel).
// Inner loop over the 4 position-parts (e[43] in VGPRs, per-position
// denominator via DPP wave-reduce -> lane-63 LDS write -> 16-way tree ->
// invD broadcast, 2 plain __syncthreads per part). This exact structure
// measured 248.6 us total / ~40 us kernel in R2 with absmax 0; the
// pipelined rewrites (R3-R7) all regressed to ~160-245 us kernel via a
// 236 MB/dispatch scratch-traffic signature that no register-budget or
// scalarization change removed. Restoring the verified optimum.
// Per-thread live set (43 e + 5 acc + temps ~= 60) fits the 64-VGPR budget
// of the default 8-waves/EU target, so SROA keeps e[] in registers.
// ---------------------------------------------------------------------------
__global__ __launch_bounds__(1024, 4)
void fused_kernel(const float* __restrict__ x, float* __restrict__ out)
{
    __shared__ float sP[kMaxPP * 16];     // per-(position, wave) partial sums
    __shared__ float sInvD[kMaxPP];
    __shared__ float sred[16];

    const int tid  = threadIdx.x;
    const int lane = tid & 63;
    const int wid  = tid >> 6;
    const int b    = blockIdx.x;

    float S0 = 0.f, S1x = 0.f, S1y = 0.f, S2x = 0.f, S2y = 0.f;

    for (int part = 0; part < kParts; ++part) {
        const int  start = part * 42;
        const bool full  = (part == 3);   // part 3 owns 43 positions

        const float* __restrict__ xc =
            x + (size_t)b * kP * kC + (size_t)start * kC + tid;

        float e[kMaxPP];
        #pragma unroll
        for (int i = 0; i < kMaxPP; ++i)
            e[i] = xc[(size_t)i * kC];    // p = start+i <= 168 always in-bounds

        #pragma unroll
        for (int i = 0; i < kMaxPP; ++i)
            e[i] = fast_exp2(e[i] * kLog2e);

        if (!full) e[42] = 0.0f;          // mask the duplicated position

        // per-position wave partial sums on the VALU pipe
        #pragma unroll
        for (int i = 0; i < kMaxPP; ++i) {
            const float s = wave_sum_dpp(e[i]);
            if (lane == 63) sP[i * 16 + wid] = s;
        }
        __syncthreads();

        if (tid < kMaxPP) {
            float d = 0.f;
            #pragma unroll
            for (int w = 0; w < 16; ++w)
                d += sP[tid * 16 + w];
            sInvD[tid] = 1.0f / (d + 1e-30f); // masked position: 0 * huge = 0
        }
        __syncthreads();

        // start = part*42 = 13*(3*part) + 3*part  ->  h = w = 3*part
        int h = 3 * part;
        int w = 3 * part;
        #pragma unroll
        for (int i = 0; i < kMaxPP; ++i) {
            const float f  = e[i] * sInvD[i];
            const float fx = (float)(h + 1);
            const float fy = (float)(w + 1);
            S0  += f;
            S1x  = fmaf(fx,      f, S1x);
            S1y  = fmaf(fy,      f, S1y);
            S2x  = fmaf(fx * fx, f, S2x);
            S2y  = fmaf(fy * fy, f, S2y);
            ++w;
            if (w == kG) { w = 0; ++h; }  // branchless cndmask after unroll
        }
        // Reuse of sP/sInvD across parts is race-free: a wave only writes
        // sP for part k+1 after passing barrier2 of part k, which wave 0
        // (the sInvD writer/sP reader) has also passed.
    }

    // det epilogue per (b, c) and block-wide mean contribution
    const float s   = S0 + kEps;
    const float is  = 1.0f / s;
    const float mx  = S1x * is;
    const float my  = S1y * is;
    const float nx  = S2x - mx * (2.0f * S1x - mx * S0);
    const float ny  = S2y - my * (2.0f * S1y - my * S0);
    const float t   = (nx + ny) * is * kInv169;
    float det = t * t * kZ;

    #pragma unroll
    for (int m = 1; m < 64; m <<= 1)
        det += __shfl_xor(det, m);

    if (lane == 0) sred[wid] = det;
    __syncthreads();
    if (wid == 0) {
        float v = (lane < 16) ? sred[lane] : 0.0f;
        #pragma unroll
        for (int m = 1; m < 16; m <<= 1)
            v += __shfl_xor(v, m);
        if (lane == 0) atomicAdd(out, v * kScale);
    }
}

extern "C" void kernel_launch(void* const* d_in, const int* in_sizes, int n_in,
                              void* d_out, int out_size, void* d_ws, size_t ws_size,
                              hipStream_t stream)
{
    const float* x   = (const float*)d_in[0];
    float*       out = (float*)d_out;

    // out is tiny (scalar compare); R2 measured this memset as ~free.
    hipMemsetAsync(out, 0, sizeof(float) * (size_t)out_size, stream);
    fused_kernel<<<dim3(kB), dim3(1024), 0, stream>>>(x, out);
}